// Round 9
// baseline (136.250 us; speedup 1.0000x reference)
//
#include <hip/hip_runtime.h>

// Problem constants (from reference setup_inputs)
#define F_FACES 6144
#define VN      5000

// sqrt(625 * log2(e))  -- C pre-scale: exp2 arg = ai + aj + 2*dot(C'i,C'j)
#define SC_F    30.02806022f
// sqrt(4 * log2(e))    -- N pre-scale: ndot term = dot(N'i,N'j)
#define SN_F    2.40224481f
// 4 * log2(e)
#define C4_F    5.7707801635558535f

typedef float v2f __attribute__((ext_vector_type(2)));

// Raw v_exp_f32 — ~16 cyc/wave64 measured; 2 per pair = half the issue demand.
__device__ __forceinline__ float fast_exp2(float x) {
    float r; asm("v_exp_f32 %0, %1" : "=v"(r) : "v"(x)); return r;
}
// Packed f32 fma — clang lowers <2 x float> elementwise fma to v_pk_fma_f32
// on CDNA (full-rate dual-f32 since gfx90a). mul/add via operators.
__device__ __forceinline__ v2f pk_fma(v2f a, v2f b, v2f c) {
    return __builtin_elementwise_fma(a, b, c);
}

// ws layout: [0, 786432)  mesh float4 pairs (4 meshes x 6144 faces x 2)
//            [786432, +4096)  64 accumulator cells, stride 16 floats (64 B)
#define CELLS_OFF_FLOATS (4 * F_FACES * 2 * 4)   // 196608 floats

// ---------------------------------------------------------------------------
// Kernel 1: per-face quantities for 4 meshes; zeroes the 64 partial cells.
//   A = [Cx*SC, Cy*SC, Cz*SC, -|C*SC|^2]
//   B = [Nx*inv*SN, Ny*inv*SN, Nz*inv*SN, log2(L) - 4*log2e]
// B.w folds Lj and the -4*log2e constant into the normal-kernel exp2.
// ---------------------------------------------------------------------------
__global__ __launch_bounds__(256) void mesh_prep(
    const float* __restrict__ pred, const float* __restrict__ targ,
    const int* __restrict__ faces, float4* __restrict__ ws4,
    float* __restrict__ cells)
{
    const int f = blockIdx.x * 256 + threadIdx.x;
    const int m = blockIdx.y;                    // mesh id = b*2 + which
    if (blockIdx.x == 0 && m == 0 && threadIdx.x < 64)
        cells[threadIdx.x * 16] = 0.0f;
    if (f >= F_FACES) return;

    const int b = m >> 1, which = m & 1;
    const float* V = (which ? targ : pred) + b * (VN * 3);

    const int i0 = faces[3 * f + 0];
    const int i1 = faces[3 * f + 1];
    const int i2 = faces[3 * f + 2];

    const float v0x = V[3 * i0 + 0], v0y = V[3 * i0 + 1], v0z = V[3 * i0 + 2];
    const float v1x = V[3 * i1 + 0], v1y = V[3 * i1 + 1], v1z = V[3 * i1 + 2];
    const float v2x = V[3 * i2 + 0], v2y = V[3 * i2 + 1], v2z = V[3 * i2 + 2];

    const float Cx = (v0x + v1x + v2x) * (1.0f / 3.0f);
    const float Cy = (v0y + v1y + v2y) * (1.0f / 3.0f);
    const float Cz = (v0z + v1z + v2z) * (1.0f / 3.0f);

    const float e1x = v1x - v0x, e1y = v1y - v0y, e1z = v1z - v0z;
    const float e2x = v2x - v0x, e2y = v2y - v0y, e2z = v2z - v0z;

    const float Nx = 0.5f * (e1y * e2z - e1z * e2y);
    const float Ny = 0.5f * (e1z * e2x - e1x * e2z);
    const float Nz = 0.5f * (e1x * e2y - e1y * e2x);

    const float l2  = Nx * Nx + Ny * Ny + Nz * Nz + 1e-24f;
    const float L   = sqrtf(l2);
    const float inv = 1.0f / L;

    const float Csx = Cx * SC_F, Csy = Cy * SC_F, Csz = Cz * SC_F;
    const float a   = -(Csx * Csx + Csy * Csy + Csz * Csz);
    const float s   = inv * SN_F;

    const long base = (long)(m * F_FACES + f) * 2;
    ws4[base + 0] = make_float4(Csx, Csy, Csz, a);
    ws4[base + 1] = make_float4(Nx * s, Ny * s, Nz * s, log2f(L) - C4_F);
}

// ---------------------------------------------------------------------------
// Kernel 2: pair sums over flattened, balanced column space (r5 grid) with
// packed-f32 inner loop: the IT=4 i-rows are carried as 2x v2f chains, so
// all non-exp arithmetic issues as v_pk_*_f32 (2 FMA/inst).
// Per 2 pairs: 16 packed inst (2cyc) + 4 v_exp_f32 (~16cyc)
//   -> 48 cyc serial per wave-iter (was 64).
// Column = (band, j-face); band = 512-row i-band of one (c,b,it).
// Total columns = 307200 = 12288 blocks x 25 (r5's best measured schedule).
// ---------------------------------------------------------------------------
#define BLK       128
#define IT        4
#define KP        (IT / 2)                // 2 packed chains
#define I_ROWS    (BLK * IT)              // 512
#define I_TILES   (F_FACES / I_ROWS)      // 12
#define W_TRI_Q   39936                   // per (c,b) triangle columns
#define TRI_TOTAL (4 * W_TRI_Q)           // 159744
#define N_BLOCKS  12288
#define CPB       25                      // columns per block

__global__ __launch_bounds__(BLK, 8) void varifold_pairs(
    const float4* __restrict__ ws4, float* __restrict__ cells)
{
    __shared__ float4 sAB[2 * CPB];
    __shared__ float  red[2];

    const int tid = threadIdx.x;
    int col = blockIdx.x * CPB;
    int remaining = CPB;
    float total = 0.0f;

    int cur_key = -1;   // (m1*16 + it) of cached i-state
    v2f C2x2[KP], C2y2[KP], C2z2[KP], Ai2[KP];
    v2f Nix2[KP], Niy2[KP], Niz2[KP], Li2[KP];
    v2f acc2[KP];
    int iIdx[IT];

    const v2f c025 = {0.25f, 0.25f};
    const v2f c016 = {0.16f, 0.16f};

    while (remaining > 0) {
        // ---- decode col -> (c, b, it, j, r, bandLeft) ----
        int c, b, it, j, r, bandLeft;
        if (col < TRI_TOTAL) {
            const int q = col / W_TRI_Q;         // 0..3
            r = col - q * W_TRI_Q;
            c = (q >> 1) ? 2 : 0; b = q & 1;
            it = 0;
            int w = F_FACES;
            while (r >= w) { r -= w; ++it; w -= I_ROWS; }
            j = it * I_ROWS + r;
            bandLeft = w - r;
        } else {
            const int lin = col - TRI_TOTAL;
            const int band = lin / F_FACES;
            r = lin - band * F_FACES;
            j = r;
            b = band / I_TILES; it = band - (band / I_TILES) * I_TILES;
            c = 1;
            bandLeft = F_FACES - r;
        }
        const bool strad = (c != 1) && (r < I_ROWS);
        int segLen = min(remaining, bandLeft);
        if (strad) segLen = min(segLen, I_ROWS - r);
        const float wOut = (c == 1) ? -1.0f : (strad ? 0.5f : 1.0f);
        const int m1 = 2 * b + (c == 2 ? 1 : 0);
        const int m2 = 2 * b + (c >= 1 ? 1 : 0);
        const float4* P1 = ws4 + (long)m1 * (F_FACES * 2);
        const float4* P2 = ws4 + (long)m2 * (F_FACES * 2);
        const int iBase = it * I_ROWS;

        // ---- (re)load i-state if band changed (pack 2 rows per v2f) ----
        const int key = m1 * 16 + it;
        if (key != cur_key) {
            cur_key = key;
#pragma unroll
            for (int kp = 0; kp < KP; ++kp) {
#pragma unroll
                for (int h = 0; h < 2; ++h) {
                    const int k = 2 * kp + h;
                    const int i = iBase + k * BLK + tid;
                    iIdx[k] = i;
                    const float4 A  = P1[2 * i + 0];
                    const float4 Bv = P1[2 * i + 1];
                    C2x2[kp][h] = 2.0f * A.x;
                    C2y2[kp][h] = 2.0f * A.y;
                    C2z2[kp][h] = 2.0f * A.z;
                    Ai2[kp][h]  = A.w;
                    Nix2[kp][h] = Bv.x; Niy2[kp][h] = Bv.y; Niz2[kp][h] = Bv.z;
                    Li2[kp][h]  = fast_exp2(Bv.w + C4_F);
                }
            }
        }
#pragma unroll
        for (int kp = 0; kp < KP; ++kp) acc2[kp] = (v2f){0.0f, 0.0f};

        // ---- stage segment's j-faces (2*segLen <= 50 float4) ----
        __syncthreads();   // previous segment done reading sAB
        if (tid < 2 * segLen) sAB[tid] = P2[2 * j + tid];
        __syncthreads();

        if (!strad) {
            for (int jj = 0; jj < segLen; ++jj) {
                const float4 a4 = sAB[2 * jj + 0];
                const float4 b4 = sAB[2 * jj + 1];
                const v2f axs = {a4.x, a4.x}, ays = {a4.y, a4.y};
                const v2f azs = {a4.z, a4.z}, aws = {a4.w, a4.w};
                const v2f bxs = {b4.x, b4.x}, bys = {b4.y, b4.y};
                const v2f bzs = {b4.z, b4.z}, bws = {b4.w, b4.w};
#pragma unroll
                for (int kp = 0; kp < KP; ++kp) {
                    v2f rr = pk_fma(C2x2[kp], axs, Ai2[kp]);
                    rr = pk_fma(C2y2[kp], ays, rr);
                    rr = pk_fma(C2z2[kp], azs, rr);
                    rr = rr + aws;
                    const v2f t0 = {fast_exp2(rr.x), fast_exp2(rr.y)};
                    v2f n = pk_fma(Nix2[kp], bxs, bws);
                    n = pk_fma(Niy2[kp], bys, n);
                    n = pk_fma(Niz2[kp], bzs, n);
                    const v2f en = {fast_exp2(n.x), fast_exp2(n.y)};
                    const v2f t2  = t0 * t0;
                    const v2f t4  = t2 * t2;
                    const v2f t8  = t4 * t4;
                    const v2f t16 = t8 * t8;
                    const v2f t24 = t16 * t8;
                    const v2f t25 = t24 * t0;
                    v2f p = pk_fma(c025, t16, t4);
                    p = pk_fma(c016, t25, p);
                    acc2[kp] = pk_fma(en, p, acc2[kp]);
                }
            }
        } else {
            for (int jj = 0; jj < segLen; ++jj) {
                const float4 a4 = sAB[2 * jj + 0];
                const float4 b4 = sAB[2 * jj + 1];
                const int jg = j + jj;
                const v2f axs = {a4.x, a4.x}, ays = {a4.y, a4.y};
                const v2f azs = {a4.z, a4.z}, aws = {a4.w, a4.w};
                const v2f bxs = {b4.x, b4.x}, bys = {b4.y, b4.y};
                const v2f bzs = {b4.z, b4.z}, bws = {b4.w, b4.w};
#pragma unroll
                for (int kp = 0; kp < KP; ++kp) {
                    v2f rr = pk_fma(C2x2[kp], axs, Ai2[kp]);
                    rr = pk_fma(C2y2[kp], ays, rr);
                    rr = pk_fma(C2z2[kp], azs, rr);
                    rr = rr + aws;
                    const v2f t0 = {fast_exp2(rr.x), fast_exp2(rr.y)};
                    v2f n = pk_fma(Nix2[kp], bxs, bws);
                    n = pk_fma(Niy2[kp], bys, n);
                    n = pk_fma(Niz2[kp], bzs, n);
                    v2f en = {fast_exp2(n.x), fast_exp2(n.y)};
                    // pair factor: 2 if j>i (upper), 1 if j==i, 0 if j<i
                    const int i0 = iIdx[2 * kp], i1 = iIdx[2 * kp + 1];
                    float f0 = (jg > i0) ? 2.0f : 0.0f; f0 = (jg == i0) ? 1.0f : f0;
                    float f1 = (jg > i1) ? 2.0f : 0.0f; f1 = (jg == i1) ? 1.0f : f1;
                    const v2f fw = {f0, f1};
                    en = en * fw;
                    const v2f t2  = t0 * t0;
                    const v2f t4  = t2 * t2;
                    const v2f t8  = t4 * t4;
                    const v2f t16 = t8 * t8;
                    const v2f t24 = t16 * t8;
                    const v2f t25 = t24 * t0;
                    v2f p = pk_fma(c025, t16, t4);
                    p = pk_fma(c016, t25, p);
                    acc2[kp] = pk_fma(en, p, acc2[kp]);
                }
            }
        }

        // fold segment into thread total with segment weight
        float part = 0.0f;
#pragma unroll
        for (int kp = 0; kp < KP; ++kp) {
            part = fmaf(acc2[kp].x, Li2[kp].x, part);
            part = fmaf(acc2[kp].y, Li2[kp].y, part);
        }
        total = fmaf(wOut, part, total);

        col += segLen; remaining -= segLen;
    }

    // block reduce (2 waves), one spread atomic per block (64 cells)
#pragma unroll
    for (int off = 32; off; off >>= 1) total += __shfl_xor(total, off);
    if ((tid & 63) == 0) red[tid >> 6] = total;
    __syncthreads();
    if (tid == 0)
        atomicAdd(&cells[(blockIdx.x & 63) * 16], red[0] + red[1]);
}

// ---------------------------------------------------------------------------
// Kernel 3: sum the 64 cells -> out[0].
// ---------------------------------------------------------------------------
__global__ __launch_bounds__(64) void finalize_sum(
    const float* __restrict__ cells, float* __restrict__ out)
{
    float v = cells[threadIdx.x * 16];
#pragma unroll
    for (int off = 32; off; off >>= 1) v += __shfl_xor(v, off);
    if (threadIdx.x == 0) out[0] = v;
}

// ---------------------------------------------------------------------------
extern "C" void kernel_launch(void* const* d_in, const int* in_sizes, int n_in,
                              void* d_out, int out_size, void* d_ws, size_t ws_size,
                              hipStream_t stream) {
    const float* pred  = (const float*)d_in[0];
    const float* targ  = (const float*)d_in[1];
    const int*   faces = (const int*)d_in[2];
    float*       out   = (float*)d_out;
    float4*      ws4   = (float4*)d_ws;                       // 786432 B
    float*       cells = (float*)d_ws + CELLS_OFF_FLOATS;     // 64 x 64B

    dim3 g1(F_FACES / 256, 4);
    mesh_prep<<<g1, 256, 0, stream>>>(pred, targ, faces, ws4, cells);

    varifold_pairs<<<dim3(N_BLOCKS), dim3(BLK), 0, stream>>>(ws4, cells);

    finalize_sum<<<dim3(1), dim3(64), 0, stream>>>(cells, out);
}

// Round 10
// 124.430 us; speedup vs baseline: 1.0950x; 1.0950x over previous
//
#include <hip/hip_runtime.h>

// Problem constants (from reference setup_inputs)
#define F_FACES 6144
#define VN      5000

// sqrt(625 * log2(e))  -- C pre-scale: exp2 arg = ai + aj + 2*dot(C'i,C'j)
#define SC_F    30.02806022f
// sqrt(4 * log2(e))    -- N pre-scale: ndot term = dot(N'i,N'j)
#define SN_F    2.40224481f
// 4 * log2(e)
#define C4_F    5.7707801635558535f

typedef float v2f __attribute__((ext_vector_type(2)));

// Raw v_exp_f32 — ~16 cyc/wave64 measured; 2 per pair = half the issue demand.
__device__ __forceinline__ float fast_exp2(float x) {
    float r; asm("v_exp_f32 %0, %1" : "=v"(r) : "v"(x)); return r;
}
// Packed f32 fma — clang lowers <2 x float> elementwise fma to v_pk_fma_f32
// on CDNA (verified r9: busy-cycles dropped ~13%).
__device__ __forceinline__ v2f pk_fma(v2f a, v2f b, v2f c) {
    return __builtin_elementwise_fma(a, b, c);
}

// ws layout: [0, 786432)  mesh float4 pairs (4 meshes x 6144 faces x 2)
//            [786432, +4096)  64 accumulator cells, stride 16 floats (64 B)
#define CELLS_OFF_FLOATS (4 * F_FACES * 2 * 4)   // 196608 floats

// ---------------------------------------------------------------------------
// Kernel 1: per-face quantities for 4 meshes; zeroes the 64 partial cells.
//   A = [Cx*SC, Cy*SC, Cz*SC, -|C*SC|^2]
//   B = [Nx*inv*SN, Ny*inv*SN, Nz*inv*SN, log2(L) - 4*log2e]
// B.w folds Lj and the -4*log2e constant into the normal-kernel exp2.
// ---------------------------------------------------------------------------
__global__ __launch_bounds__(256) void mesh_prep(
    const float* __restrict__ pred, const float* __restrict__ targ,
    const int* __restrict__ faces, float4* __restrict__ ws4,
    float* __restrict__ cells)
{
    const int f = blockIdx.x * 256 + threadIdx.x;
    const int m = blockIdx.y;                    // mesh id = b*2 + which
    if (blockIdx.x == 0 && m == 0 && threadIdx.x < 64)
        cells[threadIdx.x * 16] = 0.0f;
    if (f >= F_FACES) return;

    const int b = m >> 1, which = m & 1;
    const float* V = (which ? targ : pred) + b * (VN * 3);

    const int i0 = faces[3 * f + 0];
    const int i1 = faces[3 * f + 1];
    const int i2 = faces[3 * f + 2];

    const float v0x = V[3 * i0 + 0], v0y = V[3 * i0 + 1], v0z = V[3 * i0 + 2];
    const float v1x = V[3 * i1 + 0], v1y = V[3 * i1 + 1], v1z = V[3 * i1 + 2];
    const float v2x = V[3 * i2 + 0], v2y = V[3 * i2 + 1], v2z = V[3 * i2 + 2];

    const float Cx = (v0x + v1x + v2x) * (1.0f / 3.0f);
    const float Cy = (v0y + v1y + v2y) * (1.0f / 3.0f);
    const float Cz = (v0z + v1z + v2z) * (1.0f / 3.0f);

    const float e1x = v1x - v0x, e1y = v1y - v0y, e1z = v1z - v0z;
    const float e2x = v2x - v0x, e2y = v2y - v0y, e2z = v2z - v0z;

    const float Nx = 0.5f * (e1y * e2z - e1z * e2y);
    const float Ny = 0.5f * (e1z * e2x - e1x * e2z);
    const float Nz = 0.5f * (e1x * e2y - e1y * e2x);

    const float l2  = Nx * Nx + Ny * Ny + Nz * Nz + 1e-24f;
    const float L   = sqrtf(l2);
    const float inv = 1.0f / L;

    const float Csx = Cx * SC_F, Csy = Cy * SC_F, Csz = Cz * SC_F;
    const float a   = -(Csx * Csx + Csy * Csy + Csz * Csz);
    const float s   = inv * SN_F;

    const long base = (long)(m * F_FACES + f) * 2;
    ws4[base + 0] = make_float4(Csx, Csy, Csz, a);
    ws4[base + 1] = make_float4(Nx * s, Ny * s, Nz * s, log2f(L) - C4_F);
}

// ---------------------------------------------------------------------------
// Kernel 2: pair sums over flattened, balanced column space (r5 grid) with
// packed-f32 inner loop (v_pk_fma_f32, 2 pairs per chain).
// Per 2 pairs: 16 packed inst (2cyc) + 4 v_exp_f32 (~16cyc) = 48 cyc/iter.
// __launch_bounds__(128, 6): ~85-VGPR cap — fits the ~60 live VGPRs of the
// packed i-state WITHOUT scratch spills (r9's (128,8) forced 32 VGPRs ->
// 157 MB of spill traffic that ate the packed-math win).
// Total columns = 307200 = 12288 blocks x 25 (best measured schedule, r5).
// ---------------------------------------------------------------------------
#define BLK       128
#define IT        4
#define KP        (IT / 2)                // 2 packed chains
#define I_ROWS    (BLK * IT)              // 512
#define I_TILES   (F_FACES / I_ROWS)      // 12
#define W_TRI_Q   39936                   // per (c,b) triangle columns
#define TRI_TOTAL (4 * W_TRI_Q)           // 159744
#define N_BLOCKS  12288
#define CPB       25                      // columns per block

__global__ __launch_bounds__(BLK, 6) void varifold_pairs(
    const float4* __restrict__ ws4, float* __restrict__ cells)
{
    __shared__ float4 sAB[2 * CPB];
    __shared__ float  red[2];

    const int tid = threadIdx.x;
    int col = blockIdx.x * CPB;
    int remaining = CPB;
    float total = 0.0f;

    int cur_key = -1;   // (m1*16 + it) of cached i-state
    v2f C2x2[KP], C2y2[KP], C2z2[KP], Ai2[KP];
    v2f Nix2[KP], Niy2[KP], Niz2[KP], Li2[KP];
    v2f acc2[KP];

    const v2f c025 = {0.25f, 0.25f};
    const v2f c016 = {0.16f, 0.16f};

    while (remaining > 0) {
        // ---- decode col -> (c, b, it, j, r, bandLeft) ----
        int c, b, it, j, r, bandLeft;
        if (col < TRI_TOTAL) {
            const int q = col / W_TRI_Q;         // 0..3
            r = col - q * W_TRI_Q;
            c = (q >> 1) ? 2 : 0; b = q & 1;
            it = 0;
            int w = F_FACES;
            while (r >= w) { r -= w; ++it; w -= I_ROWS; }
            j = it * I_ROWS + r;
            bandLeft = w - r;
        } else {
            const int lin = col - TRI_TOTAL;
            const int band = lin / F_FACES;
            r = lin - band * F_FACES;
            j = r;
            b = band / I_TILES; it = band - (band / I_TILES) * I_TILES;
            c = 1;
            bandLeft = F_FACES - r;
        }
        const bool strad = (c != 1) && (r < I_ROWS);
        int segLen = min(remaining, bandLeft);
        if (strad) segLen = min(segLen, I_ROWS - r);
        const float wOut = (c == 1) ? -1.0f : (strad ? 0.5f : 1.0f);
        const int m1 = 2 * b + (c == 2 ? 1 : 0);
        const int m2 = 2 * b + (c >= 1 ? 1 : 0);
        const float4* P1 = ws4 + (long)m1 * (F_FACES * 2);
        const float4* P2 = ws4 + (long)m2 * (F_FACES * 2);
        const int iBase = it * I_ROWS;

        // ---- (re)load i-state if band changed (pack 2 rows per v2f) ----
        const int key = m1 * 16 + it;
        if (key != cur_key) {
            cur_key = key;
#pragma unroll
            for (int kp = 0; kp < KP; ++kp) {
#pragma unroll
                for (int h = 0; h < 2; ++h) {
                    const int k = 2 * kp + h;
                    const int i = iBase + k * BLK + tid;
                    const float4 A  = P1[2 * i + 0];
                    const float4 Bv = P1[2 * i + 1];
                    C2x2[kp][h] = 2.0f * A.x;
                    C2y2[kp][h] = 2.0f * A.y;
                    C2z2[kp][h] = 2.0f * A.z;
                    Ai2[kp][h]  = A.w;
                    Nix2[kp][h] = Bv.x; Niy2[kp][h] = Bv.y; Niz2[kp][h] = Bv.z;
                    Li2[kp][h]  = fast_exp2(Bv.w + C4_F);
                }
            }
        }
#pragma unroll
        for (int kp = 0; kp < KP; ++kp) acc2[kp] = (v2f){0.0f, 0.0f};

        // ---- stage segment's j-faces (2*segLen <= 50 float4) ----
        __syncthreads();   // previous segment done reading sAB
        if (tid < 2 * segLen) sAB[tid] = P2[2 * j + tid];
        __syncthreads();

        if (!strad) {
            for (int jj = 0; jj < segLen; ++jj) {
                const float4 a4 = sAB[2 * jj + 0];
                const float4 b4 = sAB[2 * jj + 1];
                const v2f axs = {a4.x, a4.x}, ays = {a4.y, a4.y};
                const v2f azs = {a4.z, a4.z}, aws = {a4.w, a4.w};
                const v2f bxs = {b4.x, b4.x}, bys = {b4.y, b4.y};
                const v2f bzs = {b4.z, b4.z}, bws = {b4.w, b4.w};
#pragma unroll
                for (int kp = 0; kp < KP; ++kp) {
                    v2f rr = pk_fma(C2x2[kp], axs, Ai2[kp]);
                    rr = pk_fma(C2y2[kp], ays, rr);
                    rr = pk_fma(C2z2[kp], azs, rr);
                    rr = rr + aws;
                    const v2f t0 = {fast_exp2(rr.x), fast_exp2(rr.y)};
                    v2f n = pk_fma(Nix2[kp], bxs, bws);
                    n = pk_fma(Niy2[kp], bys, n);
                    n = pk_fma(Niz2[kp], bzs, n);
                    const v2f en = {fast_exp2(n.x), fast_exp2(n.y)};
                    const v2f t2  = t0 * t0;
                    const v2f t4  = t2 * t2;
                    const v2f t8  = t4 * t4;
                    const v2f t16 = t8 * t8;
                    const v2f t24 = t16 * t8;
                    const v2f t25 = t24 * t0;
                    v2f p = pk_fma(c025, t16, t4);
                    p = pk_fma(c016, t25, p);
                    acc2[kp] = pk_fma(en, p, acc2[kp]);
                }
            }
        } else {
            for (int jj = 0; jj < segLen; ++jj) {
                const float4 a4 = sAB[2 * jj + 0];
                const float4 b4 = sAB[2 * jj + 1];
                const int jg = j + jj;
                const v2f axs = {a4.x, a4.x}, ays = {a4.y, a4.y};
                const v2f azs = {a4.z, a4.z}, aws = {a4.w, a4.w};
                const v2f bxs = {b4.x, b4.x}, bys = {b4.y, b4.y};
                const v2f bzs = {b4.z, b4.z}, bws = {b4.w, b4.w};
#pragma unroll
                for (int kp = 0; kp < KP; ++kp) {
                    v2f rr = pk_fma(C2x2[kp], axs, Ai2[kp]);
                    rr = pk_fma(C2y2[kp], ays, rr);
                    rr = pk_fma(C2z2[kp], azs, rr);
                    rr = rr + aws;
                    const v2f t0 = {fast_exp2(rr.x), fast_exp2(rr.y)};
                    v2f n = pk_fma(Nix2[kp], bxs, bws);
                    n = pk_fma(Niy2[kp], bys, n);
                    n = pk_fma(Niz2[kp], bzs, n);
                    v2f en = {fast_exp2(n.x), fast_exp2(n.y)};
                    // pair factor: 2 if j>i (upper), 1 if j==i, 0 if j<i
                    const int i0 = iBase + (2 * kp + 0) * BLK + tid;
                    const int i1 = iBase + (2 * kp + 1) * BLK + tid;
                    float f0 = (jg > i0) ? 2.0f : 0.0f; f0 = (jg == i0) ? 1.0f : f0;
                    float f1 = (jg > i1) ? 2.0f : 0.0f; f1 = (jg == i1) ? 1.0f : f1;
                    const v2f fw = {f0, f1};
                    en = en * fw;
                    const v2f t2  = t0 * t0;
                    const v2f t4  = t2 * t2;
                    const v2f t8  = t4 * t4;
                    const v2f t16 = t8 * t8;
                    const v2f t24 = t16 * t8;
                    const v2f t25 = t24 * t0;
                    v2f p = pk_fma(c025, t16, t4);
                    p = pk_fma(c016, t25, p);
                    acc2[kp] = pk_fma(en, p, acc2[kp]);
                }
            }
        }

        // fold segment into thread total with segment weight
        float part = 0.0f;
#pragma unroll
        for (int kp = 0; kp < KP; ++kp) {
            part = fmaf(acc2[kp].x, Li2[kp].x, part);
            part = fmaf(acc2[kp].y, Li2[kp].y, part);
        }
        total = fmaf(wOut, part, total);

        col += segLen; remaining -= segLen;
    }

    // block reduce (2 waves), one spread atomic per block (64 cells)
#pragma unroll
    for (int off = 32; off; off >>= 1) total += __shfl_xor(total, off);
    if ((tid & 63) == 0) red[tid >> 6] = total;
    __syncthreads();
    if (tid == 0)
        atomicAdd(&cells[(blockIdx.x & 63) * 16], red[0] + red[1]);
}

// ---------------------------------------------------------------------------
// Kernel 3: sum the 64 cells -> out[0].
// ---------------------------------------------------------------------------
__global__ __launch_bounds__(64) void finalize_sum(
    const float* __restrict__ cells, float* __restrict__ out)
{
    float v = cells[threadIdx.x * 16];
#pragma unroll
    for (int off = 32; off; off >>= 1) v += __shfl_xor(v, off);
    if (threadIdx.x == 0) out[0] = v;
}

// ---------------------------------------------------------------------------
extern "C" void kernel_launch(void* const* d_in, const int* in_sizes, int n_in,
                              void* d_out, int out_size, void* d_ws, size_t ws_size,
                              hipStream_t stream) {
    const float* pred  = (const float*)d_in[0];
    const float* targ  = (const float*)d_in[1];
    const int*   faces = (const int*)d_in[2];
    float*       out   = (float*)d_out;
    float4*      ws4   = (float4*)d_ws;                       // 786432 B
    float*       cells = (float*)d_ws + CELLS_OFF_FLOATS;     // 64 x 64B

    dim3 g1(F_FACES / 256, 4);
    mesh_prep<<<g1, 256, 0, stream>>>(pred, targ, faces, ws4, cells);

    varifold_pairs<<<dim3(N_BLOCKS), dim3(BLK), 0, stream>>>(ws4, cells);

    finalize_sum<<<dim3(1), dim3(64), 0, stream>>>(cells, out);
}